// Round 15
// baseline (184.069 us; speedup 1.0000x reference)
//
#include <hip/hip_runtime.h>
#include <hip/hip_fp16.h>

#define BUCKET_BITS 7
#define BUCKET_N    128     // nodes per bucket
#define SEG_CAP     1280    // edge capacity per bucket segment (lambda ~1023, +8 sigma)
#define EPB         4096    // edges per binning work-unit
#define EPT         16      // edges per thread in binning
#define OVF_CAP     16384

__device__ inline void acc_half8(float* acc, uint4 raw) {
    const __half2* h2 = (const __half2*)&raw;
#pragma unroll
    for (int k = 0; k < 4; ++k) {
        const float2 f = __half22float2(h2[k]);
        acc[2 * k]     += f.x;
        acc[2 * k + 1] += f.y;
    }
}

// ============ Phase1 (fused, block-split): transform1 | bucket binning ============
// blocks [0, tb): thread-per-node transform  p1(fp16)=x@W1rel, r1(fp16)=x@W1root+b1
// blocks [tb, tb+sb): bucket binning, RELATIVE cursors (memset 0), PACKED entries
__global__ __launch_bounds__(256) void k_phase1(
    const float* __restrict__ x, const float* __restrict__ Wrel,
    const float* __restrict__ Wroot, const float* __restrict__ bias,
    const int* __restrict__ src, const int* __restrict__ dst,
    __half* __restrict__ p1, __half* __restrict__ r1,
    int* __restrict__ cursor, int* __restrict__ seg,
    int* __restrict__ ovf_n, int2* __restrict__ ovf,
    int n_nodes, int n_edges, int nbuck, int tb)
{
    __shared__ int smem[2080];   // union: transform{wr,wo,b} | binning{hist,base}
    const int t = threadIdx.x;

    if ((int)blockIdx.x < tb) {
        // ---- transform branch ----
        float* s_wr = (float*)smem;
        float* s_wo = (float*)smem + 1024;
        float* s_b  = (float*)smem + 2048;
        for (int i = t; i < 1024; i += 256) { s_wr[i] = Wrel[i]; s_wo[i] = Wroot[i]; }
        if (t < 16) s_b[t] = bias[t];
        __syncthreads();

        const int node = blockIdx.x * 256 + t;
        if (node >= n_nodes) return;

        float accr[16], acco[16];
#pragma unroll
        for (int o = 0; o < 16; ++o) { accr[o] = 0.f; acco[o] = 0.f; }
        const float* xr = x + (size_t)node * 64;
        for (int c = 0; c < 4; ++c) {
            float4 xv[4];
#pragma unroll
            for (int u = 0; u < 4; ++u) xv[u] = *(const float4*)(xr + c * 16 + u * 4);
#pragma unroll
            for (int u = 0; u < 4; ++u) {
                const float xs[4] = {xv[u].x, xv[u].y, xv[u].z, xv[u].w};
#pragma unroll
                for (int kk = 0; kk < 4; ++kk) {
                    const int k = c * 16 + u * 4 + kk;
                    const float xk = xs[kk];
                    const float4* wr4 = (const float4*)&s_wr[k * 16];  // broadcast
                    const float4* wo4 = (const float4*)&s_wo[k * 16];
#pragma unroll
                    for (int q = 0; q < 4; ++q) {
                        const float4 wr = wr4[q], wo = wo4[q];
                        accr[q * 4 + 0] = fmaf(xk, wr.x, accr[q * 4 + 0]);
                        accr[q * 4 + 1] = fmaf(xk, wr.y, accr[q * 4 + 1]);
                        accr[q * 4 + 2] = fmaf(xk, wr.z, accr[q * 4 + 2]);
                        accr[q * 4 + 3] = fmaf(xk, wr.w, accr[q * 4 + 3]);
                        acco[q * 4 + 0] = fmaf(xk, wo.x, acco[q * 4 + 0]);
                        acco[q * 4 + 1] = fmaf(xk, wo.y, acco[q * 4 + 1]);
                        acco[q * 4 + 2] = fmaf(xk, wo.z, acco[q * 4 + 2]);
                        acco[q * 4 + 3] = fmaf(xk, wo.w, acco[q * 4 + 3]);
                    }
                }
            }
        }
        __half2 ph[8], rh[8];
#pragma unroll
        for (int k = 0; k < 8; ++k) {
            ph[k] = __floats2half2_rn(accr[2 * k], accr[2 * k + 1]);
            rh[k] = __floats2half2_rn(acco[2 * k] + s_b[2 * k],
                                      acco[2 * k + 1] + s_b[2 * k + 1]);
        }
        ((uint4*)(p1 + (size_t)node * 16))[0] = ((const uint4*)ph)[0];
        ((uint4*)(p1 + (size_t)node * 16))[1] = ((const uint4*)ph)[1];
        ((uint4*)(r1 + (size_t)node * 16))[0] = ((const uint4*)rh)[0];
        ((uint4*)(r1 + (size_t)node * 16))[1] = ((const uint4*)rh)[1];
    } else {
        // ---- binning branch ----
        int* hist = smem;
        int* base = smem + 1024;
        for (int i = t; i < nbuck; i += 256) hist[i] = 0;
        __syncthreads();

        const int e0 = ((int)blockIdx.x - tb) * EPB;
        int es[EPT], ed[EPT], ep[EPT];
#pragma unroll
        for (int k = 0; k < EPT; ++k) {
            const int e = e0 + k * 256 + t;   // coalesced per k
            if (e < n_edges) {
                ed[k] = dst[e];
                es[k] = src[e];
                ep[k] = atomicAdd(&hist[ed[k] >> BUCKET_BITS], 1);
            } else ed[k] = -1;
        }
        __syncthreads();
        for (int b = t; b < nbuck; b += 256) {
            const int h = hist[b];
            base[b] = h ? atomicAdd(&cursor[b * 16], h) : 0;
        }
        __syncthreads();
#pragma unroll
        for (int k = 0; k < EPT; ++k) {
            if (ed[k] >= 0) {
                const int b = ed[k] >> BUCKET_BITS;
                const int rel = base[b] + ep[k];
                if (rel < SEG_CAP) {
                    seg[b * SEG_CAP + rel] = (es[k] << BUCKET_BITS) | (ed[k] & (BUCKET_N - 1));
                } else {
                    const int op = atomicAdd(ovf_n, 1);   // expected never
                    if (op < OVF_CAP) ovf[op] = make_int2(es[k], ed[k]);
                }
            }
        }
    }
}

// ============ Aggregate: counting-sort (LDS only), fp16 register gather
//              (2 threads/node), fused relu+folded-W2 epilogue ======
__global__ __launch_bounds__(256) void k_aggregate(
    const __half* __restrict__ p1, const __half* __restrict__ r1,
    const int* __restrict__ seg, const int* __restrict__ cursor,
    const int* __restrict__ ovf_n, const int2* __restrict__ ovf,
    const int* __restrict__ batch,
    const float* __restrict__ W2rel, const float* __restrict__ W2root,
    const float* __restrict__ Wlin,
    float* __restrict__ s_out, float* __restrict__ T2, float* __restrict__ cntg,
    int n_nodes)
{
    __shared__ int s_src[SEG_CAP];
    __shared__ int hist[BUCKET_N];
    __shared__ int iscan[BUCKET_N];
    __shared__ int cur[BUCKET_N];
    __shared__ float s_w2r[16], s_w2o[16];
    __shared__ float sT2[64], scnt[64];
    __shared__ int s_no, s_w0;

    const int t = threadIdx.x, b = blockIdx.x;
    if (t < BUCKET_N) hist[t] = 0;
    if (t < 16) {   // fold W2 through linear head
        float ar = 0.f, ao = 0.f;
#pragma unroll
        for (int o = 0; o < 16; ++o) {
            const float wl = Wlin[o];
            ar = fmaf(W2rel[t * 16 + o], wl, ar);
            ao = fmaf(W2root[t * 16 + o], wl, ao);
        }
        s_w2r[t] = ar; s_w2o[t] = ao;
    }
    if (t < 64) { sT2[t] = 0.f; scnt[t] = 0.f; }
    if (t == 0) s_no = min(*ovf_n, OVF_CAP);
    __syncthreads();

    const int bstart = b * SEG_CAP;
    const int count = min(cursor[b * 16], SEG_CAP);

    // pass 1: packed edges into registers (<=5/thread) + histogram
    int er[5];
    int ne = 0;
    for (int i = t; i < count; i += 256) {
        er[ne] = seg[bstart + i];
        atomicAdd(&hist[er[ne] & (BUCKET_N - 1)], 1);
        ++ne;
    }
    __syncthreads();
    // wave-shuffle inclusive scan over 128 bins
    int v = 0;
    if (t < BUCKET_N) {
        v = hist[t];
#pragma unroll
        for (int off = 1; off < 64; off <<= 1) {
            const int u = __shfl_up(v, off);
            if ((t & 63) >= off) v += u;
        }
        if (t == 63) s_w0 = v;
    }
    __syncthreads();
    if (t < BUCKET_N) {
        if (t >= 64) v += s_w0;
        iscan[t] = v;
        cur[t] = v - hist[t];
    }
    __syncthreads();
    // pass 2: place src from registers
    for (int k = 0; k < ne; ++k)
        s_src[atomicAdd(&cur[er[k] & (BUCKET_N - 1)], 1)] = er[k] >> BUCKET_BITS;
    __syncthreads();

    // register accumulation: 2 threads/node, one 16B uint4 (8 halves) per edge each
    const int nl = t >> 1, half = t & 1;
    const int node = b * BUCKET_N + nl;
    if (node < n_nodes) {
        const int end = iscan[nl];
        const int beg = end - hist[nl];
        float acc[8] = {0.f, 0.f, 0.f, 0.f, 0.f, 0.f, 0.f, 0.f};
        int j = beg;
        for (; j + 2 <= end; j += 2) {
            const int s0 = s_src[j], s1 = s_src[j + 1];
            const uint4 a = *(const uint4*)(p1 + (size_t)s0 * 16 + half * 8);
            const uint4 c = *(const uint4*)(p1 + (size_t)s1 * 16 + half * 8);
            acc_half8(acc, a);
            acc_half8(acc, c);
        }
        if (j < end) {
            const uint4 a = *(const uint4*)(p1 + (size_t)s_src[j] * 16 + half * 8);
            acc_half8(acc, a);
        }
        for (int ov = 0; ov < s_no; ++ov) {   // overflow tail (expected 0)
            const int2 e = ovf[ov];
            if (e.y == node) {
                const uint4 a = *(const uint4*)(p1 + (size_t)e.x * 16 + half * 8);
                acc_half8(acc, a);
            }
        }
        // r1 (fp16): one 16B load = this half's 8 residual values
        const uint4 rraw = *(const uint4*)(r1 + (size_t)node * 16 + half * 8);
        float rv[8] = {0.f, 0.f, 0.f, 0.f, 0.f, 0.f, 0.f, 0.f};
        acc_half8(rv, rraw);
        float h[8];
#pragma unroll
        for (int k = 0; k < 8; ++k) h[k] = fmaxf(acc[k] + rv[k], 0.f);
        float ps = 0.f, pu = 0.f;
#pragma unroll
        for (int k = 0; k < 8; ++k) {
            ps = fmaf(h[k], s_w2r[half * 8 + k], ps);
            pu = fmaf(h[k], s_w2o[half * 8 + k], pu);
        }
        ps += __shfl_xor(ps, 1);
        pu += __shfl_xor(pu, 1);
        if (half == 0) {
            s_out[node] = ps;
            const int g = batch[node];
            atomicAdd(&sT2[g], pu);
            atomicAdd(&scnt[g], 1.f);
        }
    }
    __syncthreads();
    if (t < 64) {
        if (sT2[t] != 0.f) unsafeAtomicAdd(&T2[t], sT2[t]);
        if (scnt[t] != 0.f) unsafeAtomicAdd(&cntg[t], scnt[t]);
    }
}

// ============ T1 + fused finalize (last-block-done) ============
__global__ __launch_bounds__(256) void k_T1(
    const float* __restrict__ s_in, const int* __restrict__ seg,
    const int* __restrict__ cursor, const int* __restrict__ batch,
    const int* __restrict__ ovf_n, const int2* __restrict__ ovf,
    float* __restrict__ T1, const float* __restrict__ T2,
    const float* __restrict__ cntg, int* __restrict__ done,
    const float* __restrict__ b2, const float* __restrict__ Wlin,
    const float* __restrict__ blin, float* __restrict__ out,
    int n_nodes, int n_graphs)
{
    __shared__ float bins[64];
    __shared__ int sbatch[BUCKET_N];
    __shared__ int s_last;
    const int t = threadIdx.x, b = blockIdx.x;
    if (t < 64) bins[t] = 0.f;
    if (t < BUCKET_N) {
        const int node = b * BUCKET_N + t;
        sbatch[t] = (node < n_nodes) ? batch[node] : 0;   // coalesced
    }
    __syncthreads();

    const int bstart = b * SEG_CAP;
    const int count = min(cursor[b * 16], SEG_CAP);
    // 4 edges per thread for MLP on the s_in gathers (L2-resident 400KB array)
    for (int i0 = t * 4; i0 < count; i0 += 1024) {
        const int n4 = min(4, count - i0);
        int e[4];
#pragma unroll
        for (int k = 0; k < 4; ++k) if (k < n4) e[k] = seg[bstart + i0 + k];
        float vv[4];
#pragma unroll
        for (int k = 0; k < 4; ++k) if (k < n4) vv[k] = s_in[e[k] >> BUCKET_BITS];
#pragma unroll
        for (int k = 0; k < 4; ++k) if (k < n4)
            atomicAdd(&bins[sbatch[e[k] & (BUCKET_N - 1)]], vv[k]);
    }
    __syncthreads();
    if (t < 64 && bins[t] != 0.f) unsafeAtomicAdd(&T1[t], bins[t]);

    if (b == 0) {   // overflow tail (expected 0)
        const int n = min(*ovf_n, OVF_CAP);
        for (int i = t; i < n; i += 256)
            unsafeAtomicAdd(&T1[batch[ovf[i].y]], s_in[ovf[i].x]);
    }

    // ---- fused finalize: last block to finish computes out[] ----
    __threadfence();   // make this block's T1 atomics device-visible
    __syncthreads();
    if (t == 0) s_last = (atomicAdd(done, 1) == (int)gridDim.x - 1);
    __syncthreads();
    if (s_last && t < n_graphs) {
        // atomic read of T1 (device coherence point); T2/cntg written by the
        // PREVIOUS kernel -> visible via kernel boundary, plain loads fine.
        const float T1v = unsafeAtomicAdd(&T1[t], 0.f);
        float cb = 0.f;
#pragma unroll
        for (int o = 0; o < 16; ++o) cb = fmaf(b2[o], Wlin[o], cb);
        const float c = fmaxf(cntg[t], 1.f);
        out[t] = (T1v + T2[t]) / c + cb + blin[0];
    }
}

extern "C" void kernel_launch(void* const* d_in, const int* in_sizes, int n_in,
                              void* d_out, int out_size, void* d_ws, size_t ws_size,
                              hipStream_t stream) {
    const float* x       = (const float*)d_in[0];
    const int*   ei      = (const int*)d_in[1];
    const int*   batch   = (const int*)d_in[2];
    const float* W1_rel  = (const float*)d_in[3];
    const float* W1_root = (const float*)d_in[4];
    const float* b1      = (const float*)d_in[5];
    const float* W2_rel  = (const float*)d_in[6];
    const float* W2_root = (const float*)d_in[7];
    const float* b2      = (const float*)d_in[8];
    const float* Wlin    = (const float*)d_in[9];
    const float* blin    = (const float*)d_in[10];
    float* out = (float*)d_out;

    const int N = in_sizes[0] / 64;
    const int E = in_sizes[1] / 2;
    const int G = out_size;
    const int nbuck = (N + BUCKET_N - 1) >> BUCKET_BITS;   // 782 for N=100k

    const int* src = ei;
    const int* dst = ei + E;

    // ---- workspace layout; cursor..done contiguous for one small memset ----
    auto rnd4 = [](size_t v) { return (v + 3) & ~(size_t)3; };
    float* ws = (float*)d_ws;
    size_t off = 0;
    __half* p1      = (__half*)(ws + off); off += rnd4((size_t)N * 8);   // N*16 halves
    __half* r1      = (__half*)(ws + off); off += rnd4((size_t)N * 8);   // N*16 halves
    float* s_buf    = ws + off; off += rnd4((size_t)N);
    int*   cursor   = (int*)(ws + off); off += rnd4((size_t)nbuck * 16); // memset start
    int*   ovf_n    = (int*)(ws + off); off += 4;
    float* T1       = ws + off; off += rnd4((size_t)G);
    float* T2       = ws + off; off += rnd4((size_t)G);
    float* cntg     = ws + off; off += rnd4((size_t)G);
    int*   done     = (int*)(ws + off); off += 4;                        // memset end
    int*   seg      = (int*)(ws + off); off += rnd4((size_t)nbuck * SEG_CAP);
    int2*  ovf      = (int2*)(ws + off); off += rnd4((size_t)OVF_CAP * 2);

    hipMemsetAsync(cursor, 0,
                   ((size_t)nbuck * 16 + 4 + 3 * rnd4((size_t)G) + 4) * sizeof(int), stream);

    const int tb = (N + 255) / 256;        // transform blocks
    const int sb = (E + EPB - 1) / EPB;    // binning blocks

    k_phase1   <<<tb + sb, 256, 0, stream>>>(x, W1_rel, W1_root, b1, src, dst,
                                             p1, r1, cursor, seg, ovf_n, ovf,
                                             N, E, nbuck, tb);
    k_aggregate<<<nbuck, 256, 0, stream>>>(p1, r1, seg, cursor, ovf_n, ovf, batch,
                                           W2_rel, W2_root, Wlin, s_buf, T2, cntg, N);
    k_T1       <<<nbuck, 256, 0, stream>>>(s_buf, seg, cursor, batch, ovf_n, ovf,
                                           T1, T2, cntg, done, b2, Wlin, blin, out,
                                           N, G);
}

// Round 16
// 142.397 us; speedup vs baseline: 1.2927x; 1.2927x over previous
//
#include <hip/hip_runtime.h>
#include <hip/hip_fp16.h>

#define BUCKET_BITS 7
#define BUCKET_N    128     // nodes per bucket
#define SEG_CAP     1280    // edge capacity per bucket segment (lambda ~1023, +8 sigma)
#define EPB         4096    // edges per binning work-unit
#define EPT         16      // edges per thread in binning
#define OVF_CAP     16384

__device__ inline void acc_half8(float* acc, uint4 raw) {
    const __half2* h2 = (const __half2*)&raw;
#pragma unroll
    for (int k = 0; k < 4; ++k) {
        const float2 f = __half22float2(h2[k]);
        acc[2 * k]     += f.x;
        acc[2 * k + 1] += f.y;
    }
}

// ============ Phase1 (fused, block-split): transform1 | bucket binning ============
// blocks [0, tb): thread-per-node transform  p1(fp16)=x@W1rel, r1(fp16)=x@W1root+b1
// blocks [tb, tb+sb): bucket binning, RELATIVE cursors (memset 0), PACKED entries
__global__ __launch_bounds__(256) void k_phase1(
    const float* __restrict__ x, const float* __restrict__ Wrel,
    const float* __restrict__ Wroot, const float* __restrict__ bias,
    const int* __restrict__ src, const int* __restrict__ dst,
    __half* __restrict__ p1, __half* __restrict__ r1,
    int* __restrict__ cursor, int* __restrict__ seg,
    int* __restrict__ ovf_n, int2* __restrict__ ovf,
    int n_nodes, int n_edges, int nbuck, int tb)
{
    __shared__ int smem[2080];   // union: transform{wr,wo,b} | binning{hist,base}
    const int t = threadIdx.x;

    if ((int)blockIdx.x < tb) {
        // ---- transform branch ----
        float* s_wr = (float*)smem;
        float* s_wo = (float*)smem + 1024;
        float* s_b  = (float*)smem + 2048;
        for (int i = t; i < 1024; i += 256) { s_wr[i] = Wrel[i]; s_wo[i] = Wroot[i]; }
        if (t < 16) s_b[t] = bias[t];
        __syncthreads();

        const int node = blockIdx.x * 256 + t;
        if (node >= n_nodes) return;

        float accr[16], acco[16];
#pragma unroll
        for (int o = 0; o < 16; ++o) { accr[o] = 0.f; acco[o] = 0.f; }
        const float* xr = x + (size_t)node * 64;
        for (int c = 0; c < 4; ++c) {
            float4 xv[4];
#pragma unroll
            for (int u = 0; u < 4; ++u) xv[u] = *(const float4*)(xr + c * 16 + u * 4);
#pragma unroll
            for (int u = 0; u < 4; ++u) {
                const float xs[4] = {xv[u].x, xv[u].y, xv[u].z, xv[u].w};
#pragma unroll
                for (int kk = 0; kk < 4; ++kk) {
                    const int k = c * 16 + u * 4 + kk;
                    const float xk = xs[kk];
                    const float4* wr4 = (const float4*)&s_wr[k * 16];  // broadcast
                    const float4* wo4 = (const float4*)&s_wo[k * 16];
#pragma unroll
                    for (int q = 0; q < 4; ++q) {
                        const float4 wr = wr4[q], wo = wo4[q];
                        accr[q * 4 + 0] = fmaf(xk, wr.x, accr[q * 4 + 0]);
                        accr[q * 4 + 1] = fmaf(xk, wr.y, accr[q * 4 + 1]);
                        accr[q * 4 + 2] = fmaf(xk, wr.z, accr[q * 4 + 2]);
                        accr[q * 4 + 3] = fmaf(xk, wr.w, accr[q * 4 + 3]);
                        acco[q * 4 + 0] = fmaf(xk, wo.x, acco[q * 4 + 0]);
                        acco[q * 4 + 1] = fmaf(xk, wo.y, acco[q * 4 + 1]);
                        acco[q * 4 + 2] = fmaf(xk, wo.z, acco[q * 4 + 2]);
                        acco[q * 4 + 3] = fmaf(xk, wo.w, acco[q * 4 + 3]);
                    }
                }
            }
        }
        __half2 ph[8], rh[8];
#pragma unroll
        for (int k = 0; k < 8; ++k) {
            ph[k] = __floats2half2_rn(accr[2 * k], accr[2 * k + 1]);
            rh[k] = __floats2half2_rn(acco[2 * k] + s_b[2 * k],
                                      acco[2 * k + 1] + s_b[2 * k + 1]);
        }
        ((uint4*)(p1 + (size_t)node * 16))[0] = ((const uint4*)ph)[0];
        ((uint4*)(p1 + (size_t)node * 16))[1] = ((const uint4*)ph)[1];
        ((uint4*)(r1 + (size_t)node * 16))[0] = ((const uint4*)rh)[0];
        ((uint4*)(r1 + (size_t)node * 16))[1] = ((const uint4*)rh)[1];
    } else {
        // ---- binning branch ----
        int* hist = smem;
        int* base = smem + 1024;
        for (int i = t; i < nbuck; i += 256) hist[i] = 0;
        __syncthreads();

        const int e0 = ((int)blockIdx.x - tb) * EPB;
        int es[EPT], ed[EPT], ep[EPT];
#pragma unroll
        for (int k = 0; k < EPT; ++k) {
            const int e = e0 + k * 256 + t;   // coalesced per k
            if (e < n_edges) {
                ed[k] = dst[e];
                es[k] = src[e];
                ep[k] = atomicAdd(&hist[ed[k] >> BUCKET_BITS], 1);
            } else ed[k] = -1;
        }
        __syncthreads();
        for (int b = t; b < nbuck; b += 256) {
            const int h = hist[b];
            base[b] = h ? atomicAdd(&cursor[b * 16], h) : 0;
        }
        __syncthreads();
#pragma unroll
        for (int k = 0; k < EPT; ++k) {
            if (ed[k] >= 0) {
                const int b = ed[k] >> BUCKET_BITS;
                const int rel = base[b] + ep[k];
                if (rel < SEG_CAP) {
                    seg[b * SEG_CAP + rel] = (es[k] << BUCKET_BITS) | (ed[k] & (BUCKET_N - 1));
                } else {
                    const int op = atomicAdd(ovf_n, 1);   // expected never
                    if (op < OVF_CAP) ovf[op] = make_int2(es[k], ed[k]);
                }
            }
        }
    }
}

// ============ Aggregate: counting-sort (LDS only), fp16 register gather
//              (2 threads/node), fused relu+folded-W2 epilogue ======
__global__ __launch_bounds__(256) void k_aggregate(
    const __half* __restrict__ p1, const __half* __restrict__ r1,
    const int* __restrict__ seg, const int* __restrict__ cursor,
    const int* __restrict__ ovf_n, const int2* __restrict__ ovf,
    const int* __restrict__ batch,
    const float* __restrict__ W2rel, const float* __restrict__ W2root,
    const float* __restrict__ Wlin,
    float* __restrict__ s_out, float* __restrict__ T2, float* __restrict__ cntg,
    int n_nodes)
{
    __shared__ int s_src[SEG_CAP];
    __shared__ int hist[BUCKET_N];
    __shared__ int iscan[BUCKET_N];
    __shared__ int cur[BUCKET_N];
    __shared__ float s_w2r[16], s_w2o[16];
    __shared__ float sT2[64], scnt[64];
    __shared__ int s_no, s_w0;

    const int t = threadIdx.x, b = blockIdx.x;
    if (t < BUCKET_N) hist[t] = 0;
    if (t < 16) {   // fold W2 through linear head
        float ar = 0.f, ao = 0.f;
#pragma unroll
        for (int o = 0; o < 16; ++o) {
            const float wl = Wlin[o];
            ar = fmaf(W2rel[t * 16 + o], wl, ar);
            ao = fmaf(W2root[t * 16 + o], wl, ao);
        }
        s_w2r[t] = ar; s_w2o[t] = ao;
    }
    if (t < 64) { sT2[t] = 0.f; scnt[t] = 0.f; }
    if (t == 0) s_no = min(*ovf_n, OVF_CAP);
    __syncthreads();

    const int bstart = b * SEG_CAP;
    const int count = min(cursor[b * 16], SEG_CAP);

    // pass 1: packed edges into registers (<=5/thread) + histogram
    int er[5];
    int ne = 0;
    for (int i = t; i < count; i += 256) {
        er[ne] = seg[bstart + i];
        atomicAdd(&hist[er[ne] & (BUCKET_N - 1)], 1);
        ++ne;
    }
    __syncthreads();
    // wave-shuffle inclusive scan over 128 bins
    int v = 0;
    if (t < BUCKET_N) {
        v = hist[t];
#pragma unroll
        for (int off = 1; off < 64; off <<= 1) {
            const int u = __shfl_up(v, off);
            if ((t & 63) >= off) v += u;
        }
        if (t == 63) s_w0 = v;
    }
    __syncthreads();
    if (t < BUCKET_N) {
        if (t >= 64) v += s_w0;
        iscan[t] = v;
        cur[t] = v - hist[t];
    }
    __syncthreads();
    // pass 2: place src from registers
    for (int k = 0; k < ne; ++k)
        s_src[atomicAdd(&cur[er[k] & (BUCKET_N - 1)], 1)] = er[k] >> BUCKET_BITS;
    __syncthreads();

    // register accumulation: 2 threads/node, one 16B uint4 (8 halves) per edge each
    const int nl = t >> 1, half = t & 1;
    const int node = b * BUCKET_N + nl;
    if (node < n_nodes) {
        const int end = iscan[nl];
        const int beg = end - hist[nl];
        float acc[8] = {0.f, 0.f, 0.f, 0.f, 0.f, 0.f, 0.f, 0.f};
        int j = beg;
        for (; j + 2 <= end; j += 2) {
            const int s0 = s_src[j], s1 = s_src[j + 1];
            const uint4 a = *(const uint4*)(p1 + (size_t)s0 * 16 + half * 8);
            const uint4 c = *(const uint4*)(p1 + (size_t)s1 * 16 + half * 8);
            acc_half8(acc, a);
            acc_half8(acc, c);
        }
        if (j < end) {
            const uint4 a = *(const uint4*)(p1 + (size_t)s_src[j] * 16 + half * 8);
            acc_half8(acc, a);
        }
        for (int ov = 0; ov < s_no; ++ov) {   // overflow tail (expected 0)
            const int2 e = ovf[ov];
            if (e.y == node) {
                const uint4 a = *(const uint4*)(p1 + (size_t)e.x * 16 + half * 8);
                acc_half8(acc, a);
            }
        }
        // r1 (fp16): one 16B load = this half's 8 residual values
        const uint4 rraw = *(const uint4*)(r1 + (size_t)node * 16 + half * 8);
        float rv[8] = {0.f, 0.f, 0.f, 0.f, 0.f, 0.f, 0.f, 0.f};
        acc_half8(rv, rraw);
        float h[8];
#pragma unroll
        for (int k = 0; k < 8; ++k) h[k] = fmaxf(acc[k] + rv[k], 0.f);
        float ps = 0.f, pu = 0.f;
#pragma unroll
        for (int k = 0; k < 8; ++k) {
            ps = fmaf(h[k], s_w2r[half * 8 + k], ps);
            pu = fmaf(h[k], s_w2o[half * 8 + k], pu);
        }
        ps += __shfl_xor(ps, 1);
        pu += __shfl_xor(pu, 1);
        if (half == 0) {
            s_out[node] = ps;
            const int g = batch[node];
            atomicAdd(&sT2[g], pu);
            atomicAdd(&scnt[g], 1.f);
        }
    }
    __syncthreads();
    if (t < 64) {
        if (sT2[t] != 0.f) unsafeAtomicAdd(&T2[t], sT2[t]);
        if (scnt[t] != 0.f) unsafeAtomicAdd(&cntg[t], scnt[t]);
    }
}

// ============ T1: per-bucket over packed seg; batch slice cached in LDS ============
__global__ __launch_bounds__(256) void k_T1(
    const float* __restrict__ s_in, const int* __restrict__ seg,
    const int* __restrict__ cursor, const int* __restrict__ batch,
    const int* __restrict__ ovf_n, const int2* __restrict__ ovf,
    float* __restrict__ T1, int n_nodes)
{
    __shared__ float bins[64];
    __shared__ int sbatch[BUCKET_N];
    const int t = threadIdx.x, b = blockIdx.x;
    if (t < 64) bins[t] = 0.f;
    if (t < BUCKET_N) {
        const int node = b * BUCKET_N + t;
        sbatch[t] = (node < n_nodes) ? batch[node] : 0;   // coalesced
    }
    __syncthreads();

    const int bstart = b * SEG_CAP;
    const int count = min(cursor[b * 16], SEG_CAP);
    // 4 edges per thread for MLP on the s_in gathers (L2-resident 400KB array)
    for (int i0 = t * 4; i0 < count; i0 += 1024) {
        const int n4 = min(4, count - i0);
        int e[4];
#pragma unroll
        for (int k = 0; k < 4; ++k) if (k < n4) e[k] = seg[bstart + i0 + k];
        float vv[4];
#pragma unroll
        for (int k = 0; k < 4; ++k) if (k < n4) vv[k] = s_in[e[k] >> BUCKET_BITS];
#pragma unroll
        for (int k = 0; k < 4; ++k) if (k < n4)
            atomicAdd(&bins[sbatch[e[k] & (BUCKET_N - 1)]], vv[k]);
    }
    __syncthreads();
    if (t < 64 && bins[t] != 0.f) unsafeAtomicAdd(&T1[t], bins[t]);

    if (b == 0) {   // overflow tail (expected 0)
        const int n = min(*ovf_n, OVF_CAP);
        for (int i = t; i < n; i += 256)
            unsafeAtomicAdd(&T1[batch[ovf[i].y]], s_in[ovf[i].x]);
    }
}

// ============ Head: out[g] = (T1+T2)/c + b2.Wlin + blin ============
__global__ void k_finalize(
    const float* __restrict__ T1, const float* __restrict__ T2,
    const float* __restrict__ cntg, const float* __restrict__ b2,
    const float* __restrict__ Wlin, const float* __restrict__ blin,
    float* __restrict__ out, int n_graphs)
{
    const int g = threadIdx.x;
    if (g >= n_graphs) return;
    float cb = 0.f;
#pragma unroll
    for (int o = 0; o < 16; ++o) cb = fmaf(b2[o], Wlin[o], cb);
    const float c = fmaxf(cntg[g], 1.f);
    out[g] = (T1[g] + T2[g]) / c + cb + blin[0];
}

extern "C" void kernel_launch(void* const* d_in, const int* in_sizes, int n_in,
                              void* d_out, int out_size, void* d_ws, size_t ws_size,
                              hipStream_t stream) {
    const float* x       = (const float*)d_in[0];
    const int*   ei      = (const int*)d_in[1];
    const int*   batch   = (const int*)d_in[2];
    const float* W1_rel  = (const float*)d_in[3];
    const float* W1_root = (const float*)d_in[4];
    const float* b1      = (const float*)d_in[5];
    const float* W2_rel  = (const float*)d_in[6];
    const float* W2_root = (const float*)d_in[7];
    const float* b2      = (const float*)d_in[8];
    const float* Wlin    = (const float*)d_in[9];
    const float* blin    = (const float*)d_in[10];
    float* out = (float*)d_out;

    const int N = in_sizes[0] / 64;
    const int E = in_sizes[1] / 2;
    const int G = out_size;
    const int nbuck = (N + BUCKET_N - 1) >> BUCKET_BITS;   // 782 for N=100k

    const int* src = ei;
    const int* dst = ei + E;

    // ---- workspace layout; cursor..cntg contiguous for one small memset ----
    auto rnd4 = [](size_t v) { return (v + 3) & ~(size_t)3; };
    float* ws = (float*)d_ws;
    size_t off = 0;
    __half* p1      = (__half*)(ws + off); off += rnd4((size_t)N * 8);   // N*16 halves
    __half* r1      = (__half*)(ws + off); off += rnd4((size_t)N * 8);   // N*16 halves
    float* s_buf    = ws + off; off += rnd4((size_t)N);
    int*   cursor   = (int*)(ws + off); off += rnd4((size_t)nbuck * 16); // memset start
    int*   ovf_n    = (int*)(ws + off); off += 4;
    float* T1       = ws + off; off += rnd4((size_t)G);
    float* T2       = ws + off; off += rnd4((size_t)G);
    float* cntg     = ws + off; off += rnd4((size_t)G);                  // memset end
    int*   seg      = (int*)(ws + off); off += rnd4((size_t)nbuck * SEG_CAP);
    int2*  ovf      = (int2*)(ws + off); off += rnd4((size_t)OVF_CAP * 2);

    hipMemsetAsync(cursor, 0,
                   ((size_t)nbuck * 16 + 4 + 3 * rnd4((size_t)G)) * sizeof(int), stream);

    const int tb = (N + 255) / 256;        // transform blocks
    const int sb = (E + EPB - 1) / EPB;    // binning blocks

    k_phase1   <<<tb + sb, 256, 0, stream>>>(x, W1_rel, W1_root, b1, src, dst,
                                             p1, r1, cursor, seg, ovf_n, ovf,
                                             N, E, nbuck, tb);
    k_aggregate<<<nbuck, 256, 0, stream>>>(p1, r1, seg, cursor, ovf_n, ovf, batch,
                                           W2_rel, W2_root, Wlin, s_buf, T2, cntg, N);
    k_T1       <<<nbuck, 256, 0, stream>>>(s_buf, seg, cursor, batch, ovf_n, ovf, T1, N);
    k_finalize <<<1, 64, 0, stream>>>(T1, T2, cntg, b2, Wlin, blin, out, G);
}